// Round 13
// baseline (147.713 us; speedup 1.0000x reference)
//
#include <hip/hip_runtime.h>

#define B_N 128
#define C_N 1024
#define HW_N 192
#define CI_N 512
#define MROWS (B_N * HW_N)   // 24576 flat rows

typedef short bf16x8 __attribute__((ext_vector_type(8)));
typedef float f32x4 __attribute__((ext_vector_type(4)));
typedef float f32x16 __attribute__((ext_vector_type(16)));
typedef unsigned short us4 __attribute__((ext_vector_type(4)));
typedef unsigned short us8 __attribute__((ext_vector_type(8)));

__device__ __forceinline__ unsigned short f2bf(float f){
    unsigned int u = __builtin_bit_cast(unsigned int, f);
    u += 0x7fffu + ((u >> 16) & 1u);   // round-to-nearest-even
    return (unsigned short)(u >> 16);
}
__device__ __forceinline__ float bf2f(unsigned short h){
    unsigned int u = ((unsigned int)h) << 16;
    return __builtin_bit_cast(float, u);
}
__device__ __forceinline__ void gload_lds16(const void* g, void* l){
    __builtin_amdgcn_global_load_lds(
        (const __attribute__((address_space(1))) unsigned int*)g,
        (__attribute__((address_space(3))) unsigned int*)l, 16, 0, 0);
}

// ---- prep (fused): x transpose->bf16  AND  Wcat/bias/w1 conversion --------
__global__ __launch_bounds__(256) void k_prep(const float* __restrict__ x,
                                              unsigned short* __restrict__ xbT,
                                              const float* __restrict__ tw, const float* __restrict__ tb,
                                              const float* __restrict__ pw, const float* __restrict__ pb,
                                              const float* __restrict__ m1w,
                                              unsigned short* __restrict__ Wc, float* __restrict__ bias,
                                              unsigned short* __restrict__ w1b){
    __shared__ float tile[64][37];
    int b  = blockIdx.z;
    int c0 = blockIdx.y * 64;
    int n0 = blockIdx.x * 32;
    int t  = threadIdx.x;

    int fid = ((blockIdx.z * gridDim.y + blockIdx.y) * gridDim.x + blockIdx.x) * 256 + t;
    if (fid < 1024 * 1024){
        int o = fid >> 10, c = fid & 1023;
        float v = (o < 512) ? tw[(size_t)o * 1024 + c] : pw[(size_t)(o - 512) * 1024 + c];
        Wc[fid] = f2bf(v);
        if (fid < 1024) bias[fid] = (fid < 512) ? tb[fid] : pb[fid - 512];
        if (fid < 64 * HW_N) w1b[fid] = f2bf(m1w[fid]);
    }

    const float* xp = x + (size_t)b * C_N * HW_N;
    int cr = t >> 3;          // 0..31
    int nw = (t & 7) * 4;     // 0..28
    #pragma unroll
    for (int i = 0; i < 2; ++i){
        float4 v = *(const float4*)(xp + (size_t)(c0 + cr + 32 * i) * HW_N + n0 + nw);
        tile[cr + 32 * i][nw + 0] = v.x;
        tile[cr + 32 * i][nw + 1] = v.y;
        tile[cr + 32 * i][nw + 2] = v.z;
        tile[cr + 32 * i][nw + 3] = v.w;
    }
    __syncthreads();
    int nl = t >> 3;          // 0..31 output row (n)
    int j  = t & 7;           // 8-elem c group
    us8 pk;
    #pragma unroll
    for (int e = 0; e < 8; ++e)
        pk[e] = f2bf(tile[j * 8 + e][nl]);
    *(us8*)(xbT + (size_t)(b * HW_N + n0 + nl) * C_N + c0 + j * 8) = pk;
}

// ---- GEMM1: 128x128, BK=64, XCD-remapped, 2-barrier m97, 32x32x16 MFMA ----
// Per wave: 64n x 64o as 2x2 frags of 32x32 (16 MFMA/K-tile vs 32 with 16x16;
// ~17% fewer MFMA cycles at the measured 32x32 rate). C/D layout (m74/m101):
// col=lane&31, row=(reg&3)+8*(reg>>2)+4*(lane>>5).
__global__ __launch_bounds__(256, 3) void k_gemm1(const unsigned short* __restrict__ Wc,
                                               const float* __restrict__ bias,
                                               const unsigned short* __restrict__ xbT,
                                               unsigned short* __restrict__ TPt,
                                               float2* __restrict__ part){
    __shared__ __align__(16) unsigned short lW[128 * 64];  // 16KB, rows = o
    __shared__ __align__(16) unsigned short lX[128 * 64];  // 16KB, rows = n
    int bid  = blockIdx.x;
    int xcd  = bid & 7;
    int slot = bid >> 3;
    int mb = xcd * 24 + (slot >> 3);   // n-tile (0..191)
    int nb = slot & 7;                 // o-tile (0..7)
    int tid = threadIdx.x, lane = tid & 63, wave = tid >> 6;
    int wr = wave >> 1, wc = wave & 1;
    int fl = lane & 31, fh = lane >> 5;

    const unsigned short* Wg = Wc  + (size_t)(nb * 128) * C_N;
    const unsigned short* Xg = xbT + (size_t)(mb * 128) * C_N;

    int row0 = tid >> 3;                 // 0..31
    int su   = tid & 7;
    int gsw  = (su ^ (row0 & 7)) * 8;    // pre-swizzled global col (elems)
    const unsigned short* wsrc = Wg + (size_t)row0 * C_N + gsw;
    const unsigned short* xsrc = Xg + (size_t)row0 * C_N + gsw;

    f32x16 acc[2][2];
    #pragma unroll
    for (int i = 0; i < 2; ++i)
        #pragma unroll
        for (int j = 0; j < 2; ++j)
            acc[i][j] = (f32x16)(0.f);

    for (int k0 = 0; k0 < C_N; k0 += 64){
        __syncthreads();
        #pragma unroll
        for (int i = 0; i < 4; ++i){
            gload_lds16(wsrc + (size_t)(32 * i) * C_N + k0, (char*)lW + tid * 16 + i * 4096);
            gload_lds16(xsrc + (size_t)(32 * i) * C_N + k0, (char*)lX + tid * 16 + i * 4096);
        }
        __syncthreads();   // compiler drains vmcnt(0) here (m97 structure)

        #pragma unroll
        for (int kk = 0; kk < 4; ++kk){   // K-steps of 16
            bf16x8 wf[2], xf[2];
            #pragma unroll
            for (int j = 0; j < 2; ++j){
                int row = wc * 64 + j * 32 + fl;
                int un  = (kk * 2 + fh) ^ (row & 7);
                wf[j] = *(const bf16x8*)((char*)lW + row * 128 + un * 16);
            }
            #pragma unroll
            for (int i = 0; i < 2; ++i){
                int row = wr * 64 + i * 32 + fl;
                int un  = (kk * 2 + fh) ^ (row & 7);
                xf[i] = *(const bf16x8*)((char*)lX + row * 128 + un * 16);
            }
            #pragma unroll
            for (int i = 0; i < 2; ++i)
                #pragma unroll
                for (int j = 0; j < 2; ++j)
                    acc[i][j] = __builtin_amdgcn_mfma_f32_32x32x16_bf16(wf[j], xf[i], acc[i][j], 0, 0, 0);
        }
    }

    // epilogue: D col = n (fl), row = o-local (r&3) + 8*(r>>2) + 4*fh
    float s[2] = {0.f, 0.f}, q[2] = {0.f, 0.f};
    #pragma unroll
    for (int i = 0; i < 2; ++i){
        int n = mb * 128 + wr * 64 + i * 32 + fl;
        #pragma unroll
        for (int j = 0; j < 2; ++j){
            #pragma unroll
            for (int qg = 0; qg < 4; ++qg){
                int o0 = nb * 128 + wc * 64 + j * 32 + qg * 8 + fh * 4;
                float4 b4 = *(const float4*)(bias + o0);
                float v0 = acc[i][j][qg * 4 + 0] + b4.x;
                float v1 = acc[i][j][qg * 4 + 1] + b4.y;
                float v2 = acc[i][j][qg * 4 + 2] + b4.z;
                float v3 = acc[i][j][qg * 4 + 3] + b4.w;
                s[i] += v0 + v1 + v2 + v3;
                q[i] += v0*v0 + v1*v1 + v2*v2 + v3*v3;
                us4 pk;
                pk[0] = f2bf(v0); pk[1] = f2bf(v1); pk[2] = f2bf(v2); pk[3] = f2bf(v3);
                *(us4*)(TPt + (size_t)n * 1024 + o0) = pk;
            }
        }
    }
    // each lane covers half the 64-o chunk (its fh slice); pair with lane+32
    #pragma unroll
    for (int i = 0; i < 2; ++i){
        s[i] += __shfl_xor(s[i], 32);
        q[i] += __shfl_xor(q[i], 32);
    }
    if (fh == 0){   // lanes 0..31
        int chunk = nb * 2 + wc;   // 64-col chunk index (0..15)
        #pragma unroll
        for (int i = 0; i < 2; ++i){
            int n = mb * 128 + wr * 64 + i * 32 + fl;
            part[(size_t)n * 16 + chunk] = make_float2(s[i], q[i]);
        }
    }
}

// ---- GEMM2 (raw, covariance identity) + stats-fold + mask head fused ------
__global__ __launch_bounds__(256) void k_gemm2m(const unsigned short* __restrict__ TPt,
        const float2* __restrict__ part,
        const unsigned short* __restrict__ w1b, const float* __restrict__ m1b,
        const float* __restrict__ bng, const float* __restrict__ bnb,
        const float* __restrict__ bnm, const float* __restrict__ bnv,
        const float* __restrict__ m2w, const float* __restrict__ m2b,
        float* __restrict__ mask){
    __shared__ __align__(16) unsigned short lT[64 * 64];    // 8KB  theta (raw)
    __shared__ __align__(16) unsigned short lP[192 * 64];   // 24KB phi (raw)
    __shared__ __align__(16) unsigned short lF[64 * 200];   // 25.6KB F-tile (pad 200)
    __shared__ float2 stT[64];
    __shared__ float2 stP[192];
    int bid  = blockIdx.x;
    int xcd  = bid & 7;
    int slot = bid >> 3;        // 0..47
    int tn   = slot % 3;        // theta 64-row panel (0..2)
    int b    = (slot / 3) * 8 + xcd;   // bijective; same-b blocks share an XCD
    int tid = threadIdx.x, lane = tid & 63, wave = tid >> 6;
    int wr = wave >> 1, wc = wave & 1;
    int fr = lane & 15, fg = lane >> 4;

    // ---- stats fold: thread<64 -> theta row, others -> phi rows 0..191 ----
    {
        const float2* pp;
        if (tid < 64)
            pp = part + (size_t)(b * HW_N + tn * 64 + tid) * 16;        // theta chunks 0..7
        else
            pp = part + (size_t)(b * HW_N + (tid - 64)) * 16 + 8;       // phi chunks 8..15
        float S = 0.f, Q = 0.f;
        #pragma unroll
        for (int k = 0; k < 8; ++k){ float2 v = pp[k]; S += v.x; Q += v.y; }
        float mean = S * (1.f / 512.f);
        float var  = (Q - 512.f * mean * mean) * (1.f / 511.f);
        float2 r = make_float2(mean, 1.f / (sqrtf(fmaxf(var, 0.f)) + 1e-4f));
        if (tid < 64) stT[tid] = r; else stP[tid - 64] = r;
    }
    // (first K-loop barrier orders these stores before epilogue reads)

    // ---- staging setup (rule 21: pre-swizzled global src, swizzled read) --
    int row0 = tid >> 3;                 // 0..31
    int su   = tid & 7;
    int gsw  = (su ^ (row0 & 7)) * 8;    // (row0+32i)&7 == row0&7
    const unsigned short* tsrc = TPt + (size_t)(b * HW_N + tn * 64 + row0) * 1024 + gsw;
    const unsigned short* psrc = TPt + (size_t)(b * HW_N + row0) * 1024 + 512 + gsw;

    f32x4 acc[3][2][2];
    f32x4 zero = {0.f, 0.f, 0.f, 0.f};
    #pragma unroll
    for (int t = 0; t < 3; ++t)
        #pragma unroll
        for (int i = 0; i < 2; ++i)
            #pragma unroll
            for (int j = 0; j < 2; ++j)
                acc[t][i][j] = zero;

    for (int k0 = 0; k0 < CI_N; k0 += 64){
        __syncthreads();
        gload_lds16(tsrc + k0,                      (char*)lT + tid * 16);
        gload_lds16(tsrc + (size_t)32 * 1024 + k0,  (char*)lT + tid * 16 + 4096);
        #pragma unroll
        for (int i = 0; i < 6; ++i)
            gload_lds16(psrc + (size_t)(32 * i) * 1024 + k0, (char*)lP + tid * 16 + i * 4096);
        __syncthreads();   // compiler drains vmcnt(0) before barrier

        #pragma unroll
        for (int kk = 0; kk < 2; ++kk){
            bf16x8 tf[2];
            #pragma unroll
            for (int i = 0; i < 2; ++i){
                int row = wr * 32 + i * 16 + fr;
                int un  = (kk * 4 + fg) ^ (row & 7);
                tf[i] = *(const bf16x8*)((char*)lT + row * 128 + un * 16);
            }
            #pragma unroll
            for (int t = 0; t < 3; ++t){
                #pragma unroll
                for (int j = 0; j < 2; ++j){
                    int row = t * 64 + wc * 32 + j * 16 + fr;
                    int un  = (kk * 4 + fg) ^ (row & 7);
                    bf16x8 pf = *(const bf16x8*)((char*)lP + row * 128 + un * 16);
                    #pragma unroll
                    for (int i = 0; i < 2; ++i)
                        acc[t][i][j] = __builtin_amdgcn_mfma_f32_16x16x32_bf16(pf, tf[i], acc[t][i][j], 0, 0, 0);
                }
            }
        }
    }

    // ---- epilogue: identity correction, F-tile into LDS ------------------
    __syncthreads();
    #pragma unroll
    for (int t = 0; t < 3; ++t)
        #pragma unroll
        for (int i = 0; i < 2; ++i){
            int nl = wr * 32 + i * 16 + fr;        // theta row within tile
            float2 sn = stT[nl];
            #pragma unroll
            for (int j = 0; j < 2; ++j){
                int m0 = t * 64 + wc * 32 + j * 16 + fg * 4;
                us4 pk;
                #pragma unroll
                for (int r = 0; r < 4; ++r){
                    float2 sm = stP[m0 + r];
                    float F = (acc[t][i][j][r] - 512.f * sn.x * sm.x) * sn.y * sm.y * (1.0f / 512.0f);
                    pk[r] = f2bf(F);
                }
                *(us4*)((char*)lF + ((size_t)nl * 200 + m0) * 2) = pk;
            }
        }
    __syncthreads();

    // ---- mask head (proven): rows = wave*16 + (0..15) ---------------------
    f32x4 macc[4];
    #pragma unroll
    for (int j = 0; j < 4; ++j) macc[j] = zero;
    #pragma unroll
    for (int kk = 0; kk < 6; ++kk){
        bf16x8 af = *(const bf16x8*)((char*)lF + ((size_t)(wave * 16 + fr) * 200 + kk * 32 + fg * 8) * 2);
        #pragma unroll
        for (int j = 0; j < 4; ++j){
            bf16x8 bfv = *(const bf16x8*)(w1b + (size_t)(j * 16 + fr) * HW_N + kk * 32 + fg * 8);
            macc[j] = __builtin_amdgcn_mfma_f32_16x16x32_bf16(af, bfv, macc[j], 0, 0, 0);
        }
    }
    float sc[4], sh[4], bb[4], w2v[4];
    #pragma unroll
    for (int j = 0; j < 4; ++j){
        int o = j * 16 + fr;
        float s = bng[o] * rsqrtf(bnv[o] + 1e-5f);
        sc[j] = s;
        sh[j] = bnb[o] - bnm[o] * s;
        bb[j] = m1b[o];
        w2v[j] = m2w[o];
    }
    float mb2 = m2b[0];
    #pragma unroll
    for (int r = 0; r < 4; ++r){
        float y = 0.f;
        #pragma unroll
        for (int j = 0; j < 4; ++j){
            float t = fmaxf((macc[j][r] + bb[j]) * sc[j] + sh[j], 0.f);
            y += t * w2v[j];
        }
        y += __shfl_xor(y, 1);
        y += __shfl_xor(y, 2);
        y += __shfl_xor(y, 4);
        y += __shfl_xor(y, 8);
        if (fr == 0)
            mask[(size_t)b * HW_N + tn * 64 + wave * 16 + fg * 4 + r] =
                1.f + 1.f / (1.f + __expf(-(y + mb2)));   // store (1 + sigmoid)
    }
}

// ---- apply: out = x * mask1p  (fp32 x read — L3-resident after prep) ------
__global__ __launch_bounds__(256) void k_apply(const float* __restrict__ x,
                                               const float* __restrict__ mask,
                                               float* __restrict__ out){
    size_t i4 = (size_t)blockIdx.x * 256 + threadIdx.x;
    size_t e  = i4 * 4;
    float4 v = ((const float4*)x)[i4];
    size_t n = e % HW_N;                        // 192 % 4 == 0: same row for all 4
    size_t b = e / ((size_t)C_N * HW_N);
    const float* mk = mask + b * HW_N + n;
    float4 o;
    o.x = v.x * mk[0];
    o.y = v.y * mk[1];
    o.z = v.z * mk[2];
    o.w = v.w * mk[3];
    ((float4*)out)[i4] = o;
}

extern "C" void kernel_launch(void* const* d_in, const int* in_sizes, int n_in,
                              void* d_out, int out_size, void* d_ws, size_t ws_size,
                              hipStream_t stream){
    (void)in_sizes; (void)n_in; (void)out_size; (void)ws_size;
    const float* x   = (const float*)d_in[0];
    const float* tw  = (const float*)d_in[1];
    const float* tb  = (const float*)d_in[2];
    const float* pw  = (const float*)d_in[3];
    const float* pb  = (const float*)d_in[4];
    const float* m1w = (const float*)d_in[5];
    const float* m1b = (const float*)d_in[6];
    const float* bng = (const float*)d_in[7];
    const float* bnb = (const float*)d_in[8];
    const float* bnm = (const float*)d_in[9];
    const float* bnv = (const float*)d_in[10];
    const float* m2w = (const float*)d_in[11];
    const float* m2b = (const float*)d_in[12];
    float* out = (float*)d_out;

    char* ws = (char*)d_ws;
    size_t off = 0;
    unsigned short* xbT = (unsigned short*)(ws + off); off += (size_t)MROWS * C_N * 2;        // 48 MB
    unsigned short* Wc  = (unsigned short*)(ws + off); off += (size_t)1024 * 1024 * 2;        // 2 MB
    float* bias         = (float*)(ws + off);          off += 4096;
    unsigned short* TPt = (unsigned short*)(ws + off); off += (size_t)MROWS * 1024 * 2;       // 48 MB
    float* mask         = (float*)(ws + off);          off += (size_t)MROWS * 4;
    unsigned short* w1b = (unsigned short*)(ws + off); off += (size_t)64 * HW_N * 2;
    off = (off + 255) & ~(size_t)255;
    float2* part        = (float2*)(ws + off);         off += (size_t)MROWS * 16 * 8;         // 3 MB

    k_prep<<<dim3(6, 16, B_N), 256, 0, stream>>>(x, xbT, tw, tb, pw, pb, m1w, Wc, bias, w1b);
    k_gemm1<<<dim3(1536), 256, 0, stream>>>(Wc, bias, xbT, TPt, part);
    k_gemm2m<<<dim3(384), 256, 0, stream>>>(TPt, part, w1b, m1b, bng, bnb, bnm, bnv, m2w, m2b, mask);
    k_apply<<<dim3(MROWS * C_N / 4 / 256), 256, 0, stream>>>(x, mask, out);
}

// Round 14
// 139.295 us; speedup vs baseline: 1.0604x; 1.0604x over previous
//
#include <hip/hip_runtime.h>

#define B_N 128
#define C_N 1024
#define HW_N 192
#define CI_N 512
#define MROWS (B_N * HW_N)   // 24576 flat rows

typedef short bf16x8 __attribute__((ext_vector_type(8)));
typedef float f32x4 __attribute__((ext_vector_type(4)));
typedef unsigned short us4 __attribute__((ext_vector_type(4)));
typedef unsigned short us8 __attribute__((ext_vector_type(8)));

__device__ __forceinline__ unsigned short f2bf(float f){
    unsigned int u = __builtin_bit_cast(unsigned int, f);
    u += 0x7fffu + ((u >> 16) & 1u);   // round-to-nearest-even
    return (unsigned short)(u >> 16);
}
__device__ __forceinline__ float bf2f(unsigned short h){
    unsigned int u = ((unsigned int)h) << 16;
    return __builtin_bit_cast(float, u);
}
__device__ __forceinline__ void gload_lds16(const void* g, void* l){
    __builtin_amdgcn_global_load_lds(
        (const __attribute__((address_space(1))) unsigned int*)g,
        (__attribute__((address_space(3))) unsigned int*)l, 16, 0, 0);
}

// ---- prep (fused): x transpose->bf16  AND  Wcat/bias/w1 conversion --------
__global__ __launch_bounds__(256) void k_prep(const float* __restrict__ x,
                                              unsigned short* __restrict__ xbT,
                                              const float* __restrict__ tw, const float* __restrict__ tb,
                                              const float* __restrict__ pw, const float* __restrict__ pb,
                                              const float* __restrict__ m1w,
                                              unsigned short* __restrict__ Wc, float* __restrict__ bias,
                                              unsigned short* __restrict__ w1b){
    __shared__ float tile[64][37];
    int b  = blockIdx.z;
    int c0 = blockIdx.y * 64;
    int n0 = blockIdx.x * 32;
    int t  = threadIdx.x;

    int fid = ((blockIdx.z * gridDim.y + blockIdx.y) * gridDim.x + blockIdx.x) * 256 + t;
    if (fid < 1024 * 1024){
        int o = fid >> 10, c = fid & 1023;
        float v = (o < 512) ? tw[(size_t)o * 1024 + c] : pw[(size_t)(o - 512) * 1024 + c];
        Wc[fid] = f2bf(v);
        if (fid < 1024) bias[fid] = (fid < 512) ? tb[fid] : pb[fid - 512];
        if (fid < 64 * HW_N) w1b[fid] = f2bf(m1w[fid]);
    }

    const float* xp = x + (size_t)b * C_N * HW_N;
    int cr = t >> 3;          // 0..31
    int nw = (t & 7) * 4;     // 0..28
    #pragma unroll
    for (int i = 0; i < 2; ++i){
        float4 v = *(const float4*)(xp + (size_t)(c0 + cr + 32 * i) * HW_N + n0 + nw);
        tile[cr + 32 * i][nw + 0] = v.x;
        tile[cr + 32 * i][nw + 1] = v.y;
        tile[cr + 32 * i][nw + 2] = v.z;
        tile[cr + 32 * i][nw + 3] = v.w;
    }
    __syncthreads();
    int nl = t >> 3;          // 0..31 output row (n)
    int j  = t & 7;           // 8-elem c group
    us8 pk;
    #pragma unroll
    for (int e = 0; e < 8; ++e)
        pk[e] = f2bf(tile[j * 8 + e][nl]);
    *(us8*)(xbT + (size_t)(b * HW_N + n0 + nl) * C_N + c0 + j * 8) = pk;
}

// ---- GEMM1 (proven: 128x128, BK=64, XCD-remapped, 2-barrier m97, 16x16x32).
// 32x32 MFMA variant REJECTED (R12): 32-row fragment span over 8 LDS column
// slots = irreducible 4-way bank conflict (6.3M cycles, -14%).
__global__ __launch_bounds__(256, 3) void k_gemm1(const unsigned short* __restrict__ Wc,
                                               const float* __restrict__ bias,
                                               const unsigned short* __restrict__ xbT,
                                               unsigned short* __restrict__ TPt,
                                               float2* __restrict__ part){
    __shared__ __align__(16) unsigned short lW[128 * 64];  // 16KB, rows = o
    __shared__ __align__(16) unsigned short lX[128 * 64];  // 16KB, rows = n
    int bid  = blockIdx.x;
    int xcd  = bid & 7;
    int slot = bid >> 3;
    int mb = xcd * 24 + (slot >> 3);   // n-tile (0..191)
    int nb = slot & 7;                 // o-tile (0..7)
    int tid = threadIdx.x, lane = tid & 63, wave = tid >> 6;
    int wr = wave >> 1, wc = wave & 1;
    int fr = lane & 15, fg = lane >> 4;

    const unsigned short* Wg = Wc  + (size_t)(nb * 128) * C_N;
    const unsigned short* Xg = xbT + (size_t)(mb * 128) * C_N;

    int row0 = tid >> 3;                 // 0..31
    int su   = tid & 7;
    int gsw  = (su ^ (row0 & 7)) * 8;    // pre-swizzled global col (elems)
    const unsigned short* wsrc = Wg + (size_t)row0 * C_N + gsw;
    const unsigned short* xsrc = Xg + (size_t)row0 * C_N + gsw;

    f32x4 acc[4][4];
    f32x4 zero = {0.f, 0.f, 0.f, 0.f};
    #pragma unroll
    for (int i = 0; i < 4; ++i)
        #pragma unroll
        for (int j = 0; j < 4; ++j)
            acc[i][j] = zero;

    for (int k0 = 0; k0 < C_N; k0 += 64){
        __syncthreads();
        #pragma unroll
        for (int i = 0; i < 4; ++i){
            gload_lds16(wsrc + (size_t)(32 * i) * C_N + k0, (char*)lW + tid * 16 + i * 4096);
            gload_lds16(xsrc + (size_t)(32 * i) * C_N + k0, (char*)lX + tid * 16 + i * 4096);
        }
        __syncthreads();   // compiler drains vmcnt(0) here (m97 structure)

        #pragma unroll
        for (int kk = 0; kk < 2; ++kk){
            bf16x8 wf[4], xf[4];
            #pragma unroll
            for (int j = 0; j < 4; ++j){
                int row = wc * 64 + j * 16 + fr;
                int un  = (kk * 4 + fg) ^ (row & 7);
                wf[j] = *(const bf16x8*)((char*)lW + row * 128 + un * 16);
            }
            #pragma unroll
            for (int i = 0; i < 4; ++i){
                int row = wr * 64 + i * 16 + fr;
                int un  = (kk * 4 + fg) ^ (row & 7);
                xf[i] = *(const bf16x8*)((char*)lX + row * 128 + un * 16);
            }
            #pragma unroll
            for (int i = 0; i < 4; ++i)
                #pragma unroll
                for (int j = 0; j < 4; ++j)
                    acc[i][j] = __builtin_amdgcn_mfma_f32_16x16x32_bf16(wf[j], xf[i], acc[i][j], 0, 0, 0);
        }
    }

    // epilogue: D[row=o (fg*4+r within frag j), col=n (fr within frag i)]
    float s[4] = {0.f,0.f,0.f,0.f}, q[4] = {0.f,0.f,0.f,0.f};
    #pragma unroll
    for (int i = 0; i < 4; ++i){
        int n = mb * 128 + wr * 64 + i * 16 + fr;
        #pragma unroll
        for (int j = 0; j < 4; ++j){
            int o0 = nb * 128 + wc * 64 + j * 16 + fg * 4;
            float4 b4 = *(const float4*)(bias + o0);
            float v0 = acc[i][j][0] + b4.x;
            float v1 = acc[i][j][1] + b4.y;
            float v2 = acc[i][j][2] + b4.z;
            float v3 = acc[i][j][3] + b4.w;
            s[i] += v0 + v1 + v2 + v3;
            q[i] += v0*v0 + v1*v1 + v2*v2 + v3*v3;
            us4 pk;
            pk[0] = f2bf(v0); pk[1] = f2bf(v1); pk[2] = f2bf(v2); pk[3] = f2bf(v3);
            *(us4*)(TPt + (size_t)n * 1024 + o0) = pk;
        }
    }
    #pragma unroll
    for (int i = 0; i < 4; ++i){
        s[i] += __shfl_xor(s[i], 16); s[i] += __shfl_xor(s[i], 32);
        q[i] += __shfl_xor(q[i], 16); q[i] += __shfl_xor(q[i], 32);
    }
    if (lane < 16){   // fg == 0
        int chunk = nb * 2 + wc;   // 64-col chunk index (0..15)
        #pragma unroll
        for (int i = 0; i < 4; ++i){
            int n = mb * 128 + wr * 64 + i * 16 + fr;
            part[(size_t)n * 16 + chunk] = make_float2(s[i], q[i]);
        }
    }
}

// ---- GEMM2 (raw, covariance identity) + stats-fold + mask head fused ------
// XCD-aware decode: all 3 tn-blocks of a batch b land on XCD b&7 consecutively
// -> phi panel (192KB) fetched from HBM once, L2-hit for the other two.
__global__ __launch_bounds__(256) void k_gemm2m(const unsigned short* __restrict__ TPt,
        const float2* __restrict__ part,
        const unsigned short* __restrict__ w1b, const float* __restrict__ m1b,
        const float* __restrict__ bng, const float* __restrict__ bnb,
        const float* __restrict__ bnm, const float* __restrict__ bnv,
        const float* __restrict__ m2w, const float* __restrict__ m2b,
        float* __restrict__ mask){
    __shared__ __align__(16) unsigned short lT[64 * 64];    // 8KB  theta (raw)
    __shared__ __align__(16) unsigned short lP[192 * 64];   // 24KB phi (raw)
    __shared__ __align__(16) unsigned short lF[64 * 200];   // 25.6KB F-tile (pad 200)
    __shared__ float2 stT[64];
    __shared__ float2 stP[192];
    int bid  = blockIdx.x;
    int xcd  = bid & 7;
    int slot = bid >> 3;        // 0..47
    int tn   = slot % 3;        // theta 64-row panel (0..2)
    int b    = (slot / 3) * 8 + xcd;   // bijective; same-b blocks share an XCD
    int tid = threadIdx.x, lane = tid & 63, wave = tid >> 6;
    int wr = wave >> 1, wc = wave & 1;
    int fr = lane & 15, fg = lane >> 4;

    // ---- stats fold: thread<64 -> theta row, others -> phi rows 0..191 ----
    {
        const float2* pp;
        if (tid < 64)
            pp = part + (size_t)(b * HW_N + tn * 64 + tid) * 16;        // theta chunks 0..7
        else
            pp = part + (size_t)(b * HW_N + (tid - 64)) * 16 + 8;       // phi chunks 8..15
        float S = 0.f, Q = 0.f;
        #pragma unroll
        for (int k = 0; k < 8; ++k){ float2 v = pp[k]; S += v.x; Q += v.y; }
        float mean = S * (1.f / 512.f);
        float var  = (Q - 512.f * mean * mean) * (1.f / 511.f);
        float2 r = make_float2(mean, 1.f / (sqrtf(fmaxf(var, 0.f)) + 1e-4f));
        if (tid < 64) stT[tid] = r; else stP[tid - 64] = r;
    }
    // (first K-loop barrier orders these stores before epilogue reads)

    // ---- staging setup (rule 21: pre-swizzled global src, swizzled read) --
    int row0 = tid >> 3;                 // 0..31
    int su   = tid & 7;
    int gsw  = (su ^ (row0 & 7)) * 8;    // (row0+32i)&7 == row0&7
    const unsigned short* tsrc = TPt + (size_t)(b * HW_N + tn * 64 + row0) * 1024 + gsw;
    const unsigned short* psrc = TPt + (size_t)(b * HW_N + row0) * 1024 + 512 + gsw;

    f32x4 acc[3][2][2];
    f32x4 zero = {0.f, 0.f, 0.f, 0.f};
    #pragma unroll
    for (int t = 0; t < 3; ++t)
        #pragma unroll
        for (int i = 0; i < 2; ++i)
            #pragma unroll
            for (int j = 0; j < 2; ++j)
                acc[t][i][j] = zero;

    for (int k0 = 0; k0 < CI_N; k0 += 64){
        __syncthreads();
        gload_lds16(tsrc + k0,                      (char*)lT + tid * 16);
        gload_lds16(tsrc + (size_t)32 * 1024 + k0,  (char*)lT + tid * 16 + 4096);
        #pragma unroll
        for (int i = 0; i < 6; ++i)
            gload_lds16(psrc + (size_t)(32 * i) * 1024 + k0, (char*)lP + tid * 16 + i * 4096);
        __syncthreads();   // compiler drains vmcnt(0) before barrier

        #pragma unroll
        for (int kk = 0; kk < 2; ++kk){
            bf16x8 tf[2];
            #pragma unroll
            for (int i = 0; i < 2; ++i){
                int row = wr * 32 + i * 16 + fr;
                int un  = (kk * 4 + fg) ^ (row & 7);
                tf[i] = *(const bf16x8*)((char*)lT + row * 128 + un * 16);
            }
            #pragma unroll
            for (int t = 0; t < 3; ++t){
                #pragma unroll
                for (int j = 0; j < 2; ++j){
                    int row = t * 64 + wc * 32 + j * 16 + fr;
                    int un  = (kk * 4 + fg) ^ (row & 7);
                    bf16x8 pf = *(const bf16x8*)((char*)lP + row * 128 + un * 16);
                    #pragma unroll
                    for (int i = 0; i < 2; ++i)
                        acc[t][i][j] = __builtin_amdgcn_mfma_f32_16x16x32_bf16(pf, tf[i], acc[t][i][j], 0, 0, 0);
                }
            }
        }
    }

    // ---- epilogue: identity correction, F-tile into LDS ------------------
    __syncthreads();
    #pragma unroll
    for (int t = 0; t < 3; ++t)
        #pragma unroll
        for (int i = 0; i < 2; ++i){
            int nl = wr * 32 + i * 16 + fr;        // theta row within tile
            float2 sn = stT[nl];
            #pragma unroll
            for (int j = 0; j < 2; ++j){
                int m0 = t * 64 + wc * 32 + j * 16 + fg * 4;
                us4 pk;
                #pragma unroll
                for (int r = 0; r < 4; ++r){
                    float2 sm = stP[m0 + r];
                    float F = (acc[t][i][j][r] - 512.f * sn.x * sm.x) * sn.y * sm.y * (1.0f / 512.0f);
                    pk[r] = f2bf(F);
                }
                *(us4*)((char*)lF + ((size_t)nl * 200 + m0) * 2) = pk;
            }
        }
    __syncthreads();

    // ---- mask head (proven): rows = wave*16 + (0..15) ---------------------
    f32x4 macc[4];
    #pragma unroll
    for (int j = 0; j < 4; ++j) macc[j] = zero;
    #pragma unroll
    for (int kk = 0; kk < 6; ++kk){
        bf16x8 af = *(const bf16x8*)((char*)lF + ((size_t)(wave * 16 + fr) * 200 + kk * 32 + fg * 8) * 2);
        #pragma unroll
        for (int j = 0; j < 4; ++j){
            bf16x8 bfv = *(const bf16x8*)(w1b + (size_t)(j * 16 + fr) * HW_N + kk * 32 + fg * 8);
            macc[j] = __builtin_amdgcn_mfma_f32_16x16x32_bf16(af, bfv, macc[j], 0, 0, 0);
        }
    }
    float sc[4], sh[4], bb[4], w2v[4];
    #pragma unroll
    for (int j = 0; j < 4; ++j){
        int o = j * 16 + fr;
        float s = bng[o] * rsqrtf(bnv[o] + 1e-5f);
        sc[j] = s;
        sh[j] = bnb[o] - bnm[o] * s;
        bb[j] = m1b[o];
        w2v[j] = m2w[o];
    }
    float mb2 = m2b[0];
    #pragma unroll
    for (int r = 0; r < 4; ++r){
        float y = 0.f;
        #pragma unroll
        for (int j = 0; j < 4; ++j){
            float t = fmaxf((macc[j][r] + bb[j]) * sc[j] + sh[j], 0.f);
            y += t * w2v[j];
        }
        y += __shfl_xor(y, 1);
        y += __shfl_xor(y, 2);
        y += __shfl_xor(y, 4);
        y += __shfl_xor(y, 8);
        if (fr == 0)
            mask[(size_t)b * HW_N + tn * 64 + wave * 16 + fg * 4 + r] =
                1.f + 1.f / (1.f + __expf(-(y + mb2)));   // store (1 + sigmoid)
    }
}

// ---- apply: out = x * mask1p  (fp32 x read — L3-resident after prep) ------
__global__ __launch_bounds__(256) void k_apply(const float* __restrict__ x,
                                               const float* __restrict__ mask,
                                               float* __restrict__ out){
    size_t i4 = (size_t)blockIdx.x * 256 + threadIdx.x;
    size_t e  = i4 * 4;
    float4 v = ((const float4*)x)[i4];
    size_t n = e % HW_N;                        // 192 % 4 == 0: same row for all 4
    size_t b = e / ((size_t)C_N * HW_N);
    const float* mk = mask + b * HW_N + n;
    float4 o;
    o.x = v.x * mk[0];
    o.y = v.y * mk[1];
    o.z = v.z * mk[2];
    o.w = v.w * mk[3];
    ((float4*)out)[i4] = o;
}

extern "C" void kernel_launch(void* const* d_in, const int* in_sizes, int n_in,
                              void* d_out, int out_size, void* d_ws, size_t ws_size,
                              hipStream_t stream){
    (void)in_sizes; (void)n_in; (void)out_size; (void)ws_size;
    const float* x   = (const float*)d_in[0];
    const float* tw  = (const float*)d_in[1];
    const float* tb  = (const float*)d_in[2];
    const float* pw  = (const float*)d_in[3];
    const float* pb  = (const float*)d_in[4];
    const float* m1w = (const float*)d_in[5];
    const float* m1b = (const float*)d_in[6];
    const float* bng = (const float*)d_in[7];
    const float* bnb = (const float*)d_in[8];
    const float* bnm = (const float*)d_in[9];
    const float* bnv = (const float*)d_in[10];
    const float* m2w = (const float*)d_in[11];
    const float* m2b = (const float*)d_in[12];
    float* out = (float*)d_out;

    char* ws = (char*)d_ws;
    size_t off = 0;
    unsigned short* xbT = (unsigned short*)(ws + off); off += (size_t)MROWS * C_N * 2;        // 48 MB
    unsigned short* Wc  = (unsigned short*)(ws + off); off += (size_t)1024 * 1024 * 2;        // 2 MB
    float* bias         = (float*)(ws + off);          off += 4096;
    unsigned short* TPt = (unsigned short*)(ws + off); off += (size_t)MROWS * 1024 * 2;       // 48 MB
    float* mask         = (float*)(ws + off);          off += (size_t)MROWS * 4;
    unsigned short* w1b = (unsigned short*)(ws + off); off += (size_t)64 * HW_N * 2;
    off = (off + 255) & ~(size_t)255;
    float2* part        = (float2*)(ws + off);         off += (size_t)MROWS * 16 * 8;         // 3 MB

    k_prep<<<dim3(6, 16, B_N), 256, 0, stream>>>(x, xbT, tw, tb, pw, pb, m1w, Wc, bias, w1b);
    k_gemm1<<<dim3(1536), 256, 0, stream>>>(Wc, bias, xbT, TPt, part);
    k_gemm2m<<<dim3(384), 256, 0, stream>>>(TPt, part, w1b, m1b, bng, bnb, bnm, bnv, m2w, m2b, mask);
    k_apply<<<dim3(MROWS * C_N / 4 / 256), 256, 0, stream>>>(x, mask, out);
}